// Round 1
// 235.926 us; speedup vs baseline: 1.3358x; 1.3358x over previous
//
#include <hip/hip_runtime.h>

// Soft-DTW gradient, batch=64, 256x256, gamma=0.01 — forward/backward-DP form.
// R15: replace the weight-based backward E-recursion with the independent
// suffix DP:  E(i,j) = exp2( K2*theta(i,j) + F'tot - F'(i,j) - B'(i,j) ),
// where B is soft-DTW run from the bottom-right corner (same recurrence on the
// index-reversed matrix). F and B are INDEPENDENT -> run concurrently on 128
// blocks (blocks 0..63 = F of element b, 64..127 = B of element b-64): the
// serial critical path halves (191 wavefront steps instead of 382), and no
// softmin weights are computed or stored (drops rcp/muls, halves DP stores).
// DP core is the proven R14 structure: 128 threads (2 waves), lane L owns
// virtual rows 2L,2L+1, 4-col groups, skew m=g+L, branch-free double-buffered
// LDS exchange with an LDS-only barrier. Scaled domain V' = V/(gamma*ln2).
// Epilogue (after device-scope flag barrier over 128 blocks): each block
// computes 2 output rows of out = mean_b exp2(...), fused with batch mean.
// ws: F planes [64][65536] f32, B planes [64][65536] f32, counter u32
// (same footprint/offsets as R14).

#define MM 256
#define NN 256
#define R 2              // rows per virtual lane
#define NB 64            // batch elements
#define NBLK 128         // DP blocks: 64 forward + 64 backward
#define NVL 128          // virtual lanes per block
#define SBIG 1.0e12f     // "infinity" in the scaled domain
#define K2   144.269504089f     // 1/(gamma*ln2) = (1/gamma)*log2(e)

__device__ __forceinline__ float f4get(const float4& v, int k) {
    switch (k) { case 0: return v.x; case 1: return v.y; case 2: return v.z; default: return v.w; }
}
__device__ __forceinline__ int iclamp(int x, int lo, int hi) {
    return x < lo ? lo : (x > hi ? hi : x);
}
// LDS-visibility-only workgroup barrier: does NOT drain vmcnt, so global
// prefetch loads / value stores stay in flight across it.
__device__ __forceinline__ void lds_barrier() {
    asm volatile("s_waitcnt lgkmcnt(0)\n\ts_barrier" ::: "memory");
}

// One soft-DTW value DP (forward recurrence) over the virtual matrix.
// REV=false: virtual == physical (computes F').
// REV=true : virtual (i,j) = physical (255-i, 255-j)  (computes B', stored
//            mirrored so Vp[i][j] = B'(i,j) in physical coordinates).
template<bool REV>
__device__ __forceinline__ void run_dp(const float* __restrict__ th,
                                       float* __restrict__ Vp,
                                       float4 (*xb)[NVL + 1])
{
    const int L = threadIdx.x;

    float vprev[R];
    #pragma unroll
    for (int r = 0; r < R; ++r) vprev[r] = SBIG;
    float4 rec = make_float4(SBIG, SBIG, SBIG, SBIG);
    float prevW = SBIG;
    float4 botV4 = make_float4(SBIG, SBIG, SBIG, SBIG);
    float4 thB[3][R];
    #pragma unroll
    for (int p = 0; p < 3; ++p)
        #pragma unroll
        for (int r = 0; r < R; ++r) thB[p][r] = make_float4(0.f, 0.f, 0.f, 0.f);

    if (threadIdx.x == 0) {
        xb[0][0] = make_float4(SBIG, SBIG, SBIG, SBIG);
        xb[1][0] = make_float4(SBIG, SBIG, SBIG, SBIG);
    }
    __syncthreads();

    auto body = [&](const int LD, const int CU, const int m) {
        const int g = m - L;
        const int gl = iclamp(g + 2, 0, 63);        // prefetch distance 2
        #pragma unroll
        for (int r = 0; r < R; ++r) {
            const int vr = 2 * L + r;               // virtual row
            if (REV) {
                const float4 t = *(const float4*)(th + (255 - vr) * NN + (252 - 4 * gl));
                thB[LD][r] = make_float4(t.w, t.z, t.y, t.x);   // reverse cols
            } else {
                thB[LD][r] = *(const float4*)(th + vr * NN + 4 * gl);
            }
        }
        if (g >= 0 && g <= 63) {
            const float4 topV = rec;                // row above, cols 4g..4g+3
            const float vd0 = (g == 0) ? ((L == 0) ? 0.0f : SBIG) : prevW;
            float vbuf[R][4];
            #pragma unroll
            for (int cc = 0; cc < 4; ++cc) {
                float vu = f4get(topV, cc);
                float vd = (cc == 0) ? vd0 : f4get(topV, cc - 1);
                #pragma unroll
                for (int r = 0; r < R; ++r) {
                    const float vl = vprev[r];
                    const float mn = fminf(vl, fminf(vd, vu));
                    const float el = exp2f(mn - vl);
                    const float ed = exp2f(mn - vd);
                    const float eu = exp2f(mn - vu);
                    const float ss = el + ed + eu;
                    const float a  = mn - log2f(ss);            // scaled softmin
                    const float v  = fmaf(f4get(thB[CU][r], cc), K2, a);
                    vbuf[r][cc] = v;
                    vd = vl;
                    vu = v;
                    vprev[r] = v;
                }
            }
            botV4 = make_float4(vbuf[R - 1][0], vbuf[R - 1][1], vbuf[R - 1][2], vbuf[R - 1][3]);
            #pragma unroll
            for (int r = 0; r < R; ++r) {
                const int vr = 2 * L + r;
                if (REV)
                    *(float4*)(Vp + (255 - vr) * NN + (252 - 4 * g)) =
                        make_float4(vbuf[r][3], vbuf[r][2], vbuf[r][1], vbuf[r][0]);
                else
                    *(float4*)(Vp + vr * NN + 4 * g) =
                        make_float4(vbuf[r][0], vbuf[r][1], vbuf[r][2], vbuf[r][3]);
            }
        }
        // ---- branch-free exchange (LDS-only barrier) ----
        xb[m & 1][L + 1] = botV4;
        lds_barrier();
        prevW = rec.w;
        rec = xb[m & 1][L];
    };
    for (int k = 0; k < 195; k += 3) {              // m = -2 .. 192
        body(0, 1, k - 2);
        body(1, 2, k - 1);
        body(2, 0, k);
    }
}

__global__ __launch_bounds__(128) void dtw_fb(
    const float* __restrict__ D,
    float* __restrict__ out,          // [256][256]
    float* __restrict__ ws)
{
    __shared__ float4 xb[2][NVL + 1];

    const int blk = blockIdx.x;
    const bool rev = blk >= NB;
    const int b = rev ? blk - NB : blk;
    const float* __restrict__ th = D + (size_t)b * (MM * NN);
    float* __restrict__ Fp = ws + (size_t)b * (MM * NN);
    float* __restrict__ Bp = ws + (size_t)(NB + b) * (MM * NN);
    unsigned* ctr = (unsigned*)(ws + (size_t)2 * NB * (MM * NN));

    if (rev) run_dp<true >(th, Bp, xb);
    else     run_dp<false>(th, Fp, xb);

    // ---------------- device-scope barrier (128 blocks) ----------------
    __syncthreads();                   // both waves done issuing stores
    __threadfence();                   // each wave drains its own stores
    __syncthreads();                   // wave 1's fence complete before release
    if (threadIdx.x == 0)
        __hip_atomic_fetch_add(ctr, 1u, __ATOMIC_ACQ_REL, __HIP_MEMORY_SCOPE_AGENT);
    unsigned cnt;
    do {
        cnt = __hip_atomic_load(ctr, __ATOMIC_ACQUIRE, __HIP_MEMORY_SCOPE_AGENT);
        if (cnt < NBLK) __builtin_amdgcn_s_sleep(2);
    } while (cnt < NBLK);
    __builtin_amdgcn_fence(__ATOMIC_ACQUIRE, "agent");   // invalidate caches

    // ---------------- fused epilogue + batch mean ----------------
    // E_b(i,j) = exp2( K2*theta + F'tot_b - F'_b(i,j) - B'_b(i,j) );
    // block blk owns output rows 2*blk, 2*blk+1.
    {
        const int row = 2 * blk + (threadIdx.x >> 6);
        const int col = 4 * (threadIdx.x & 63);
        const size_t off = (size_t)row * NN + col;
        float4 acc = make_float4(0.f, 0.f, 0.f, 0.f);
        for (int p = 0; p < NB; ++p) {
            const float* __restrict__ thp = D + (size_t)p * (MM * NN);
            const float* __restrict__ fp  = ws + (size_t)p * (MM * NN);
            const float* __restrict__ bp  = ws + (size_t)(NB + p) * (MM * NN);
            const float Ft = fp[MM * NN - 1];                 // F'tot = F'(M,N)
            const float4 t4 = *(const float4*)(thp + off);
            const float4 f4 = *(const float4*)(fp + off);
            const float4 b4 = *(const float4*)(bp + off);
            acc.x += exp2f(fmaf(t4.x, K2, (Ft - f4.x) - b4.x));
            acc.y += exp2f(fmaf(t4.y, K2, (Ft - f4.y) - b4.y));
            acc.z += exp2f(fmaf(t4.z, K2, (Ft - f4.z) - b4.z));
            acc.w += exp2f(fmaf(t4.w, K2, (Ft - f4.w) - b4.w));
        }
        const float inv = 1.0f / (float)NB;
        *(float4*)(out + off) =
            make_float4(acc.x * inv, acc.y * inv, acc.z * inv, acc.w * inv);
    }
}

extern "C" void kernel_launch(void* const* d_in, const int* in_sizes, int n_in,
                              void* d_out, int out_size, void* d_ws, size_t ws_size,
                              hipStream_t stream) {
    const float* D = (const float*)d_in[0];
    float* out = (float*)d_out;
    float* ws = (float*)d_ws;

    // zero the barrier counter (ws is re-poisoned 0xAA before every launch)
    hipMemsetAsync(ws + (size_t)2 * NB * (MM * NN), 0, sizeof(unsigned), stream);
    dtw_fb<<<dim3(NBLK), dim3(128), 0, stream>>>(D, out, ws);
}